// Round 10
// baseline (197.675 us; speedup 1.0000x reference)
//
#include <hip/hip_runtime.h>

#define FM_NNZ   819200
#define FM_BATCH 16384
#define FM_DIM   100000
#define FM_K     128
#define NB_SHIFT 12          // 4096 cols/bucket -> 1MB bf16 window (L2-resident)
#define NBUCK    25          // ceil(100000 / 4096)
#define UNR      4           // uint4 gather instructions in flight (16 nnz)

// ---------------- pass 1: convert v (f32) -> bf16 pairs in workspace ----------
// vb[c*64 + l] packs dims (2l, 2l+1) of column c as bf16 (RNE). 25.6 MB.
// Read in pass 2 as uint4: vb4[c*16 + ql] = dims 8*ql .. 8*ql+7.

static __device__ __forceinline__ uint32_t f2bf(float f) {
    uint32_t u = __float_as_uint(f);
    return (u + 0x7fffu + ((u >> 16) & 1u)) >> 16;   // RNE
}

__global__ __launch_bounds__(256) void cvt_kernel(const float* __restrict__ v,
                                                  uint32_t* __restrict__ vb) {
    const float4* __restrict__ v4 = (const float4*)v;
    uint2* __restrict__ o = (uint2*)vb;
    const int n = (FM_DIM * FM_K) / 4;
    for (int i = blockIdx.x * blockDim.x + threadIdx.x; i < n;
         i += gridDim.x * blockDim.x) {
        const float4 x = v4[i];
        uint2 r;
        r.x = f2bf(x.x) | (f2bf(x.y) << 16);
        r.y = f2bf(x.z) | (f2bf(x.w) << 16);
        o[i] = r;
    }
}

// -- pass 2: bucket-sorted lists + 4-column uint4 gathers (1KB/instruction) ----
// 2048 blocks x 4 waves = 32 waves/CU exactly resident; each wave owns 2 rows.
// Phase 1: bin (col,val) by col-bucket into LDS lists (once). Phase 2: walk the
// sorted list; lane-group grp=lane>>4 serves entry i+4u+grp, ql=lane&15 serves
// dims 8ql..8ql+7 -> each gather instruction fetches 4 columns x 256B = 1KB,
// maximizing bytes in flight under the ~10 vmem-instructions/CU cap, and the
// sorted sweep keeps those hits inside a ~1MB L2-resident window.

__global__ __launch_bounds__(256, 8) void fm_fwd_kernel(
    const float* __restrict__ vals,
    const int*   __restrict__ row_idx,
    const int*   __restrict__ col_idx,
    const float* __restrict__ w0,
    const float* __restrict__ w_,
    const uint32_t* __restrict__ vb,   // bf16-packed v
    float*       __restrict__ out)
{
    __shared__ uint2 lists[4][2][128];          // [wave][row][entry] = (col, val)

    const int wave = threadIdx.x >> 6;
    const int lane = threadIdx.x & 63;
    const int grp  = lane >> 4;                 // which list entry this lane serves
    const int ql   = lane & 15;                 // dim-quarter: dims 8*ql .. 8*ql+7
    const int wid  = blockIdx.x * 4 + wave;     // 0..8191
    const int row0 = 2 * wid;

    // --- three lower_bound searches on sorted row_idx ---
    int s[3];
    #pragma unroll
    for (int q = 0; q < 3; ++q) {
        const int key = row0 + q;
        int lo = 0, hi = FM_NNZ;
        while (lo < hi) {
            const int mid = (lo + hi) >> 1;
            if (row_idx[mid] < key) lo = mid + 1; else hi = mid;
        }
        s[q] = lo;
    }
    const int s0 = s[0], s1 = s[1], s2 = s[2];

    // --- 4 register slots: A,B = row0, C,D = row1 (row nnz <= 128) ---
    int cA, cB, cC, cD;  float aA, aB, aC, aD;  int bA, bB, bC, bD;
    {
        int idx, ic; bool ok;
        idx = s0 + lane;      ok = idx < s1; ic = min(idx, FM_NNZ - 1);
        cA = col_idx[ic]; aA = ok ? vals[ic] : 0.f; bA = ok ? (cA >> NB_SHIFT) : 127;
        idx = s0 + 64 + lane; ok = idx < s1; ic = min(idx, FM_NNZ - 1);
        cB = col_idx[ic]; aB = ok ? vals[ic] : 0.f; bB = ok ? (cB >> NB_SHIFT) : 127;
        idx = s1 + lane;      ok = idx < s2; ic = min(idx, FM_NNZ - 1);
        cC = col_idx[ic]; aC = ok ? vals[ic] : 0.f; bC = ok ? (cC >> NB_SHIFT) : 127;
        idx = s1 + 64 + lane; ok = idx < s2; ic = min(idx, FM_NNZ - 1);
        cD = col_idx[ic]; aD = ok ? vals[ic] : 0.f; bD = ok ? (cD >> NB_SHIFT) : 127;
    }

    // --- linear term (off the hot path): lane-parallel w gathers ---
    float lin0 = aA * w_[cA] + aB * w_[cB];
    float lin1 = aC * w_[cC] + aD * w_[cD];

    // --- phase 1: ballot-histogram + prefix scatter into bucket-sorted lists ---
    const unsigned long long lt = (1ull << lane) - 1ull;
    int total0, total1;
    {
        int posA = -1, posB = -1, run = 0;
        for (int p = 0; p < NBUCK; ++p) {
            const unsigned long long mA = __ballot(bA == p);
            const unsigned long long mB = __ballot(bB == p);
            const int nA = __popcll(mA);
            if (bA == p) posA = run + __popcll(mA & lt);
            if (bB == p) posB = run + nA + __popcll(mB & lt);
            run += nA + __popcll(mB);
        }
        total0 = run;
        if (posA >= 0) lists[wave][0][posA] = make_uint2((uint32_t)cA, __float_as_uint(aA));
        if (posB >= 0) lists[wave][0][posB] = make_uint2((uint32_t)cB, __float_as_uint(aB));
    }
    {
        int posC = -1, posD = -1, run = 0;
        for (int p = 0; p < NBUCK; ++p) {
            const unsigned long long mC = __ballot(bC == p);
            const unsigned long long mD = __ballot(bD == p);
            const int nC = __popcll(mC);
            if (bC == p) posC = run + __popcll(mC & lt);
            if (bD == p) posD = run + nC + __popcll(mD & lt);
            run += nC + __popcll(mD);
        }
        total1 = run;
        if (posC >= 0) lists[wave][1][posC] = make_uint2((uint32_t)cC, __float_as_uint(aC));
        if (posD >= 0) lists[wave][1][posD] = make_uint2((uint32_t)cD, __float_as_uint(aD));
    }
    __syncthreads();

    const uint4* __restrict__ vb4 = (const uint4*)vb;   // col stride = 16 uint4

    // --- phase 2: sorted-list walk, UNR uint4 gathers (4 cols each) in flight ---
    float xv[8], sq[8];
    float part0, part1;

#define ROWWALK(r, total, partr)                                              \
    {                                                                         \
        _Pragma("unroll")                                                     \
        for (int d = 0; d < 8; ++d) { xv[d] = 0.f; sq[d] = 0.f; }             \
        for (int i = 0; i < (total); i += 4 * UNR) {                          \
            uint2 ca[UNR];                                                    \
            uint4 vv[UNR];                                                    \
            _Pragma("unroll")                                                 \
            for (int u = 0; u < UNR; ++u) {                                   \
                const int e = min(i + 4 * u + grp, (total) - 1);              \
                ca[u] = lists[wave][r][e];   /* 4 distinct addrs: bcast */    \
            }                                                                 \
            _Pragma("unroll")                                                 \
            for (int u = 0; u < UNR; ++u) {                                   \
                vv[u] = vb4[(size_t)ca[u].x * 16 + ql];  /* 1KB/instr */      \
            }                                                                 \
            __builtin_amdgcn_sched_barrier(0);                                \
            _Pragma("unroll")                                                 \
            for (int u = 0; u < UNR; ++u) {                                   \
                const float aj = (i + 4 * u + grp < (total))                  \
                                     ? __uint_as_float(ca[u].y) : 0.f;        \
                const uint32_t wd[4] = {vv[u].x, vv[u].y, vv[u].z, vv[u].w};  \
                _Pragma("unroll")                                             \
                for (int q2 = 0; q2 < 4; ++q2) {                              \
                    const float vlo = __uint_as_float(wd[q2] << 16);          \
                    const float vhi = __uint_as_float(wd[q2] & 0xffff0000u);  \
                    const float tl = aj * vlo, th = aj * vhi;                 \
                    xv[2*q2]   += tl;                                         \
                    xv[2*q2+1] += th;                                         \
                    sq[2*q2]   = fmaf(tl, vlo, sq[2*q2]);                     \
                    sq[2*q2+1] = fmaf(th, vhi, sq[2*q2+1]);                   \
                }                                                             \
            }                                                                 \
        }                                                                     \
        float px = 0.f, sqs = 0.f;                                            \
        _Pragma("unroll")                                                     \
        for (int d = 0; d < 8; ++d) {                                         \
            float t = xv[d];                                                  \
            t += __shfl_xor(t, 16);                                           \
            t += __shfl_xor(t, 32);     /* sum the 4 nnz-subsets */           \
            px = fmaf(t, t, px);                                              \
            sqs += sq[d];                                                     \
        }                                                                     \
        partr = ((lane < 16) ? px : 0.f) - sqs;  /* count each dim^2 once */  \
    }

    ROWWALK(0, total0, part0)
    ROWWALK(1, total1, part1)
#undef ROWWALK

    // --- reduce across lanes ---
    #pragma unroll
    for (int off = 32; off > 0; off >>= 1) {
        part0 += __shfl_down(part0, off);
        part1 += __shfl_down(part1, off);
        lin0  += __shfl_down(lin0,  off);
        lin1  += __shfl_down(lin1,  off);
    }
    if (lane == 0) {
        const float bias = w0[0];
        out[row0]     = bias + lin0 + 0.5f * part0;
        out[row0 + 1] = bias + lin1 + 0.5f * part1;
    }
}

extern "C" void kernel_launch(void* const* d_in, const int* in_sizes, int n_in,
                              void* d_out, int out_size, void* d_ws, size_t ws_size,
                              hipStream_t stream) {
    // setup_inputs order: vals, row_idx, col_idx, batch(scalar), w0, w, v
    const float* vals    = (const float*)d_in[0];
    const int*   row_idx = (const int*)  d_in[1];
    const int*   col_idx = (const int*)  d_in[2];
    const float* w0      = (const float*)d_in[4];
    const float* w       = (const float*)d_in[5];
    const float* v       = (const float*)d_in[6];
    float*       out     = (float*)d_out;
    uint32_t*    vb      = (uint32_t*)d_ws;          // 25.6 MB bf16 copy of v

    cvt_kernel<<<1024, 256, 0, stream>>>(v, vb);
    fm_fwd_kernel<<<FM_BATCH / 8, 256, 0, stream>>>(
        vals, row_idx, col_idx, w0, w, vb, out);
}

// Round 11
// 183.516 us; speedup vs baseline: 1.0772x; 1.0772x over previous
//
#include <hip/hip_runtime.h>

#define FM_NNZ   819200
#define FM_BATCH 16384
#define FM_DIM   100000
#define FM_K     128
#define NB_SHIFT 12          // 4096 cols/bucket -> 1MB bf16 window (L2-resident)
#define NBUCK    25          // ceil(100000 / 4096)
#define UNR      2           // uint4 gather instructions in flight (8 nnz, 2KB)

// ---------------- pass 1: convert v (f32) -> bf16 pairs in workspace ----------
// vb[c*64 + l] packs dims (2l, 2l+1) of column c as bf16 (RNE). 25.6 MB.
// Read in pass 2 as uint4: vb4[c*16 + ql] = dims 8*ql .. 8*ql+7.

static __device__ __forceinline__ uint32_t f2bf(float f) {
    uint32_t u = __float_as_uint(f);
    return (u + 0x7fffu + ((u >> 16) & 1u)) >> 16;   // RNE
}

__global__ __launch_bounds__(256) void cvt_kernel(const float* __restrict__ v,
                                                  uint32_t* __restrict__ vb) {
    const float4* __restrict__ v4 = (const float4*)v;
    uint2* __restrict__ o = (uint2*)vb;
    const int n = (FM_DIM * FM_K) / 4;
    for (int i = blockIdx.x * blockDim.x + threadIdx.x; i < n;
         i += gridDim.x * blockDim.x) {
        const float4 x = v4[i];
        uint2 r;
        r.x = f2bf(x.x) | (f2bf(x.y) << 16);
        r.y = f2bf(x.z) | (f2bf(x.w) << 16);
        o[i] = r;
    }
}

// -- pass 2: bucket-sorted lists + 4-column uint4 gathers (1KB/instruction) ----
// 2048 blocks x 4 waves = 32 waves/CU exactly resident; each wave owns 2 rows.
// UNR=2 keeps in-flight arrays at 12 VGPR so the (256,8) 64-VGPR cap holds
// WITHOUT scratch spill (r10's 126MB WRITE_SIZE spill regression).

__global__ __launch_bounds__(256, 8) void fm_fwd_kernel(
    const float* __restrict__ vals,
    const int*   __restrict__ row_idx,
    const int*   __restrict__ col_idx,
    const float* __restrict__ w0,
    const float* __restrict__ w_,
    const uint32_t* __restrict__ vb,   // bf16-packed v
    float*       __restrict__ out)
{
    __shared__ uint2 lists[4][2][128];          // [wave][row][entry] = (col, val)

    const int wave = threadIdx.x >> 6;
    const int lane = threadIdx.x & 63;
    const int grp  = lane >> 4;                 // which list entry this lane serves
    const int ql   = lane & 15;                 // dim-quarter: dims 8*ql .. 8*ql+7
    const int wid  = blockIdx.x * 4 + wave;     // 0..8191
    const int row0 = 2 * wid;

    // --- three lower_bound searches on sorted row_idx ---
    int s[3];
    #pragma unroll
    for (int q = 0; q < 3; ++q) {
        const int key = row0 + q;
        int lo = 0, hi = FM_NNZ;
        while (lo < hi) {
            const int mid = (lo + hi) >> 1;
            if (row_idx[mid] < key) lo = mid + 1; else hi = mid;
        }
        s[q] = lo;
    }
    const int s0 = s[0], s1 = s[1], s2 = s[2];

    // --- 4 register slots: A,B = row0, C,D = row1 (row nnz <= 128) ---
    int cA, cB, cC, cD;  float aA, aB, aC, aD;  int bA, bB, bC, bD;
    {
        int idx, ic; bool ok;
        idx = s0 + lane;      ok = idx < s1; ic = min(idx, FM_NNZ - 1);
        cA = col_idx[ic]; aA = ok ? vals[ic] : 0.f; bA = ok ? (cA >> NB_SHIFT) : 127;
        idx = s0 + 64 + lane; ok = idx < s1; ic = min(idx, FM_NNZ - 1);
        cB = col_idx[ic]; aB = ok ? vals[ic] : 0.f; bB = ok ? (cB >> NB_SHIFT) : 127;
        idx = s1 + lane;      ok = idx < s2; ic = min(idx, FM_NNZ - 1);
        cC = col_idx[ic]; aC = ok ? vals[ic] : 0.f; bC = ok ? (cC >> NB_SHIFT) : 127;
        idx = s1 + 64 + lane; ok = idx < s2; ic = min(idx, FM_NNZ - 1);
        cD = col_idx[ic]; aD = ok ? vals[ic] : 0.f; bD = ok ? (cD >> NB_SHIFT) : 127;
    }

    // --- linear term (off the hot path): lane-parallel w gathers ---
    float lin0 = aA * w_[cA] + aB * w_[cB];
    float lin1 = aC * w_[cC] + aD * w_[cD];

    // --- phase 1: ballot-histogram + prefix scatter into bucket-sorted lists ---
    const unsigned long long lt = (1ull << lane) - 1ull;
    int total0, total1;
    {
        int posA = -1, posB = -1, run = 0;
        for (int p = 0; p < NBUCK; ++p) {
            const unsigned long long mA = __ballot(bA == p);
            const unsigned long long mB = __ballot(bB == p);
            const int nA = __popcll(mA);
            if (bA == p) posA = run + __popcll(mA & lt);
            if (bB == p) posB = run + nA + __popcll(mB & lt);
            run += nA + __popcll(mB);
        }
        total0 = run;
        if (posA >= 0) lists[wave][0][posA] = make_uint2((uint32_t)cA, __float_as_uint(aA));
        if (posB >= 0) lists[wave][0][posB] = make_uint2((uint32_t)cB, __float_as_uint(aB));
    }
    {
        int posC = -1, posD = -1, run = 0;
        for (int p = 0; p < NBUCK; ++p) {
            const unsigned long long mC = __ballot(bC == p);
            const unsigned long long mD = __ballot(bD == p);
            const int nC = __popcll(mC);
            if (bC == p) posC = run + __popcll(mC & lt);
            if (bD == p) posD = run + nC + __popcll(mD & lt);
            run += nC + __popcll(mD);
        }
        total1 = run;
        if (posC >= 0) lists[wave][1][posC] = make_uint2((uint32_t)cC, __float_as_uint(aC));
        if (posD >= 0) lists[wave][1][posD] = make_uint2((uint32_t)cD, __float_as_uint(aD));
    }
    __syncthreads();

    const uint4* __restrict__ vb4 = (const uint4*)vb;   // col stride = 16 uint4

    // --- phase 2: sorted-list walk, UNR uint4 gathers (4 cols each) in flight ---
    float xv[8], sq[8];
    float part0, part1;

#define ROWWALK(r, total, partr)                                              \
    {                                                                         \
        _Pragma("unroll")                                                     \
        for (int d = 0; d < 8; ++d) { xv[d] = 0.f; sq[d] = 0.f; }             \
        for (int i = 0; i < (total); i += 4 * UNR) {                          \
            uint2 ca[UNR];                                                    \
            uint4 vv[UNR];                                                    \
            _Pragma("unroll")                                                 \
            for (int u = 0; u < UNR; ++u) {                                   \
                const int e = min(i + 4 * u + grp, (total) - 1);              \
                ca[u] = lists[wave][r][e];   /* 4 distinct addrs: bcast */    \
            }                                                                 \
            _Pragma("unroll")                                                 \
            for (int u = 0; u < UNR; ++u) {                                   \
                vv[u] = vb4[(size_t)ca[u].x * 16 + ql];  /* 1KB/instr */      \
            }                                                                 \
            _Pragma("unroll")                                                 \
            for (int u = 0; u < UNR; ++u) {                                   \
                const float aj = (i + 4 * u + grp < (total))                  \
                                     ? __uint_as_float(ca[u].y) : 0.f;        \
                const uint32_t wd[4] = {vv[u].x, vv[u].y, vv[u].z, vv[u].w};  \
                _Pragma("unroll")                                             \
                for (int q2 = 0; q2 < 4; ++q2) {                              \
                    const float vlo = __uint_as_float(wd[q2] << 16);          \
                    const float vhi = __uint_as_float(wd[q2] & 0xffff0000u);  \
                    const float tl = aj * vlo, th = aj * vhi;                 \
                    xv[2*q2]   += tl;                                         \
                    xv[2*q2+1] += th;                                         \
                    sq[2*q2]   = fmaf(tl, vlo, sq[2*q2]);                     \
                    sq[2*q2+1] = fmaf(th, vhi, sq[2*q2+1]);                   \
                }                                                             \
            }                                                                 \
        }                                                                     \
        float px = 0.f, sqs = 0.f;                                            \
        _Pragma("unroll")                                                     \
        for (int d = 0; d < 8; ++d) {                                         \
            float t = xv[d];                                                  \
            t += __shfl_xor(t, 16);                                           \
            t += __shfl_xor(t, 32);     /* sum the 4 nnz-subsets */           \
            px = fmaf(t, t, px);                                              \
            sqs += sq[d];                                                     \
        }                                                                     \
        partr = ((lane < 16) ? px : 0.f) - sqs;  /* count each dim^2 once */  \
    }

    ROWWALK(0, total0, part0)
    ROWWALK(1, total1, part1)
#undef ROWWALK

    // --- reduce across lanes ---
    #pragma unroll
    for (int off = 32; off > 0; off >>= 1) {
        part0 += __shfl_down(part0, off);
        part1 += __shfl_down(part1, off);
        lin0  += __shfl_down(lin0,  off);
        lin1  += __shfl_down(lin1,  off);
    }
    if (lane == 0) {
        const float bias = w0[0];
        out[row0]     = bias + lin0 + 0.5f * part0;
        out[row0 + 1] = bias + lin1 + 0.5f * part1;
    }
}

extern "C" void kernel_launch(void* const* d_in, const int* in_sizes, int n_in,
                              void* d_out, int out_size, void* d_ws, size_t ws_size,
                              hipStream_t stream) {
    // setup_inputs order: vals, row_idx, col_idx, batch(scalar), w0, w, v
    const float* vals    = (const float*)d_in[0];
    const int*   row_idx = (const int*)  d_in[1];
    const int*   col_idx = (const int*)  d_in[2];
    const float* w0      = (const float*)d_in[4];
    const float* w       = (const float*)d_in[5];
    const float* v       = (const float*)d_in[6];
    float*       out     = (float*)d_out;
    uint32_t*    vb      = (uint32_t*)d_ws;          // 25.6 MB bf16 copy of v

    cvt_kernel<<<1024, 256, 0, stream>>>(v, vb);
    fm_fwd_kernel<<<FM_BATCH / 8, 256, 0, stream>>>(
        vals, row_idx, col_idx, w0, w, vb, out);
}

// Round 12
// 167.535 us; speedup vs baseline: 1.1799x; 1.0954x over previous
//
#include <hip/hip_runtime.h>

#define FM_NNZ   819200
#define FM_BATCH 16384
#define FM_DIM   100000
#define FM_K     128
#define NB_SHIFT 12          // 4096 cols/bucket -> 1MB bf16 window (L2-resident)
#define NBUCK    25          // ceil(100000 / 4096)
#define UNR      4           // uint4 gather instructions in flight (16 nnz, 4KB)

// ---------------- pass 1: convert v (f32) -> bf16 pairs in workspace ----------
// vb[c*64 + l] packs dims (2l, 2l+1) of column c as bf16 (RNE). 25.6 MB.
// Read in pass 2 as uint4: vb4[c*16 + ql] = dims 8*ql .. 8*ql+7.

static __device__ __forceinline__ uint32_t f2bf(float f) {
    uint32_t u = __float_as_uint(f);
    return (u + 0x7fffu + ((u >> 16) & 1u)) >> 16;   // RNE
}

__global__ __launch_bounds__(256) void cvt_kernel(const float* __restrict__ v,
                                                  uint32_t* __restrict__ vb) {
    const float4* __restrict__ v4 = (const float4*)v;
    uint2* __restrict__ o = (uint2*)vb;
    const int n = (FM_DIM * FM_K) / 4;
    for (int i = blockIdx.x * blockDim.x + threadIdx.x; i < n;
         i += gridDim.x * blockDim.x) {
        const float4 x = v4[i];
        uint2 r;
        r.x = f2bf(x.x) | (f2bf(x.y) << 16);
        r.y = f2bf(x.z) | (f2bf(x.w) << 16);
        o[i] = r;
    }
}

// -- pass 2: bucket-sorted lists + 4-column uint4 gathers (1KB/instruction) ----
// launch_bounds (256,4): 128-VGPR budget so UNR=4 in-flight uint4 gathers fit
// WITHOUT scratch spill (r10/r11 spilled under the (256,8) 32-VGPR allocation).
// 16 waves/CU; instruction-cap (~10/CU) still saturated: 16 waves x 4 deep.

__global__ __launch_bounds__(256, 4) void fm_fwd_kernel(
    const float* __restrict__ vals,
    const int*   __restrict__ row_idx,
    const int*   __restrict__ col_idx,
    const float* __restrict__ w0,
    const float* __restrict__ w_,
    const uint32_t* __restrict__ vb,   // bf16-packed v
    float*       __restrict__ out)
{
    __shared__ uint2 lists[4][2][128];          // [wave][row][entry] = (col, val)

    const int wave = threadIdx.x >> 6;
    const int lane = threadIdx.x & 63;
    const int grp  = lane >> 4;                 // which list entry this lane serves
    const int ql   = lane & 15;                 // dim-quarter: dims 8*ql .. 8*ql+7
    const int wid  = blockIdx.x * 4 + wave;     // 0..8191
    const int row0 = 2 * wid;

    // --- three lower_bound searches on sorted row_idx ---
    int s[3];
    #pragma unroll
    for (int q = 0; q < 3; ++q) {
        const int key = row0 + q;
        int lo = 0, hi = FM_NNZ;
        while (lo < hi) {
            const int mid = (lo + hi) >> 1;
            if (row_idx[mid] < key) lo = mid + 1; else hi = mid;
        }
        s[q] = lo;
    }
    const int s0 = s[0], s1 = s[1], s2 = s[2];

    // --- 4 register slots: A,B = row0, C,D = row1 (row nnz <= 128) ---
    int cA, cB, cC, cD;  float aA, aB, aC, aD;  int bA, bB, bC, bD;
    {
        int idx, ic; bool ok;
        idx = s0 + lane;      ok = idx < s1; ic = min(idx, FM_NNZ - 1);
        cA = col_idx[ic]; aA = ok ? vals[ic] : 0.f; bA = ok ? (cA >> NB_SHIFT) : 127;
        idx = s0 + 64 + lane; ok = idx < s1; ic = min(idx, FM_NNZ - 1);
        cB = col_idx[ic]; aB = ok ? vals[ic] : 0.f; bB = ok ? (cB >> NB_SHIFT) : 127;
        idx = s1 + lane;      ok = idx < s2; ic = min(idx, FM_NNZ - 1);
        cC = col_idx[ic]; aC = ok ? vals[ic] : 0.f; bC = ok ? (cC >> NB_SHIFT) : 127;
        idx = s1 + 64 + lane; ok = idx < s2; ic = min(idx, FM_NNZ - 1);
        cD = col_idx[ic]; aD = ok ? vals[ic] : 0.f; bD = ok ? (cD >> NB_SHIFT) : 127;
    }

    // --- linear term (off the hot path): lane-parallel w gathers ---
    float lin0 = aA * w_[cA] + aB * w_[cB];
    float lin1 = aC * w_[cC] + aD * w_[cD];

    // --- phase 1: ballot-histogram + prefix scatter into bucket-sorted lists ---
    const unsigned long long lt = (1ull << lane) - 1ull;
    int total0, total1;
    {
        int posA = -1, posB = -1, run = 0;
        for (int p = 0; p < NBUCK; ++p) {
            const unsigned long long mA = __ballot(bA == p);
            const unsigned long long mB = __ballot(bB == p);
            const int nA = __popcll(mA);
            if (bA == p) posA = run + __popcll(mA & lt);
            if (bB == p) posB = run + nA + __popcll(mB & lt);
            run += nA + __popcll(mB);
        }
        total0 = run;
        if (posA >= 0) lists[wave][0][posA] = make_uint2((uint32_t)cA, __float_as_uint(aA));
        if (posB >= 0) lists[wave][0][posB] = make_uint2((uint32_t)cB, __float_as_uint(aB));
    }
    {
        int posC = -1, posD = -1, run = 0;
        for (int p = 0; p < NBUCK; ++p) {
            const unsigned long long mC = __ballot(bC == p);
            const unsigned long long mD = __ballot(bD == p);
            const int nC = __popcll(mC);
            if (bC == p) posC = run + __popcll(mC & lt);
            if (bD == p) posD = run + nC + __popcll(mD & lt);
            run += nC + __popcll(mD);
        }
        total1 = run;
        if (posC >= 0) lists[wave][1][posC] = make_uint2((uint32_t)cC, __float_as_uint(aC));
        if (posD >= 0) lists[wave][1][posD] = make_uint2((uint32_t)cD, __float_as_uint(aD));
    }
    __syncthreads();

    const uint4* __restrict__ vb4 = (const uint4*)vb;   // col stride = 16 uint4

    // --- phase 2: sorted-list walk, UNR uint4 gathers (4 cols each) in flight ---
    float xv[8], sq[8];
    float part0, part1;

#define ROWWALK(r, total, partr)                                              \
    {                                                                         \
        _Pragma("unroll")                                                     \
        for (int d = 0; d < 8; ++d) { xv[d] = 0.f; sq[d] = 0.f; }             \
        for (int i = 0; i < (total); i += 4 * UNR) {                          \
            uint2 ca[UNR];                                                    \
            uint4 vv[UNR];                                                    \
            _Pragma("unroll")                                                 \
            for (int u = 0; u < UNR; ++u) {                                   \
                const int e = min(i + 4 * u + grp, (total) - 1);              \
                ca[u] = lists[wave][r][e];   /* 4 distinct addrs: bcast */    \
            }                                                                 \
            _Pragma("unroll")                                                 \
            for (int u = 0; u < UNR; ++u) {                                   \
                vv[u] = vb4[(size_t)ca[u].x * 16 + ql];  /* 1KB/instr */      \
            }                                                                 \
            _Pragma("unroll")                                                 \
            for (int u = 0; u < UNR; ++u) {                                   \
                const float aj = (i + 4 * u + grp < (total))                  \
                                     ? __uint_as_float(ca[u].y) : 0.f;        \
                const uint32_t wd[4] = {vv[u].x, vv[u].y, vv[u].z, vv[u].w};  \
                _Pragma("unroll")                                             \
                for (int q2 = 0; q2 < 4; ++q2) {                              \
                    const float vlo = __uint_as_float(wd[q2] << 16);          \
                    const float vhi = __uint_as_float(wd[q2] & 0xffff0000u);  \
                    const float tl = aj * vlo, th = aj * vhi;                 \
                    xv[2*q2]   += tl;                                         \
                    xv[2*q2+1] += th;                                         \
                    sq[2*q2]   = fmaf(tl, vlo, sq[2*q2]);                     \
                    sq[2*q2+1] = fmaf(th, vhi, sq[2*q2+1]);                   \
                }                                                             \
            }                                                                 \
        }                                                                     \
        float px = 0.f, sqs = 0.f;                                            \
        _Pragma("unroll")                                                     \
        for (int d = 0; d < 8; ++d) {                                         \
            float t = xv[d];                                                  \
            t += __shfl_xor(t, 16);                                           \
            t += __shfl_xor(t, 32);     /* sum the 4 nnz-subsets */           \
            px = fmaf(t, t, px);                                              \
            sqs += sq[d];                                                     \
        }                                                                     \
        partr = ((lane < 16) ? px : 0.f) - sqs;  /* count each dim^2 once */  \
    }

    ROWWALK(0, total0, part0)
    ROWWALK(1, total1, part1)
#undef ROWWALK

    // --- reduce across lanes ---
    #pragma unroll
    for (int off = 32; off > 0; off >>= 1) {
        part0 += __shfl_down(part0, off);
        part1 += __shfl_down(part1, off);
        lin0  += __shfl_down(lin0,  off);
        lin1  += __shfl_down(lin1,  off);
    }
    if (lane == 0) {
        const float bias = w0[0];
        out[row0]     = bias + lin0 + 0.5f * part0;
        out[row0 + 1] = bias + lin1 + 0.5f * part1;
    }
}

extern "C" void kernel_launch(void* const* d_in, const int* in_sizes, int n_in,
                              void* d_out, int out_size, void* d_ws, size_t ws_size,
                              hipStream_t stream) {
    // setup_inputs order: vals, row_idx, col_idx, batch(scalar), w0, w, v
    const float* vals    = (const float*)d_in[0];
    const int*   row_idx = (const int*)  d_in[1];
    const int*   col_idx = (const int*)  d_in[2];
    const float* w0      = (const float*)d_in[4];
    const float* w       = (const float*)d_in[5];
    const float* v       = (const float*)d_in[6];
    float*       out     = (float*)d_out;
    uint32_t*    vb      = (uint32_t*)d_ws;          // 25.6 MB bf16 copy of v

    cvt_kernel<<<1024, 256, 0, stream>>>(v, vb);
    fm_fwd_kernel<<<FM_BATCH / 8, 256, 0, stream>>>(
        vals, row_idx, col_idx, w0, w, vb, out);
}